// Round 9
// baseline (334.928 us; speedup 1.0000x reference)
//
#include <hip/hip_runtime.h>
#include <stdint.h>

typedef unsigned short u16;
typedef __attribute__((ext_vector_type(8))) __bf16 bf16x8;
typedef __attribute__((ext_vector_type(4))) float f32x4;

// ---------------- scalar helpers ----------------
__device__ __forceinline__ u16 f2bf(float f) {
    uint32_t u = __float_as_uint(f);
    u += 0x7FFF + ((u >> 16) & 1);   // RNE
    return (u16)(u >> 16);
}
__device__ __forceinline__ float bf2f(u16 b) {
    return __uint_as_float(((uint32_t)b) << 16);
}
__device__ __forceinline__ float h2f(u16 h) {
    float r; uint32_t x = h;
    asm volatile("v_cvt_f32_f16_e32 %0, %1" : "=v"(r) : "v"(x));
    return r;
}
__device__ __forceinline__ u16 f2h(float f) {
    uint32_t r;
    asm volatile("v_cvt_f16_f32_e32 %0, %1" : "=v"(r) : "v"(f));
    return (u16)r;
}

// ---------------- dtype detection ----------------
// flags[0]: x/bias/out mode: 0=float32, 1=bf16(u16), 2=fp16(u16)
// flags[1]: qweight mode:    0=packed bytes, 1=one byte per int32
__global__ void detect_kernel(const uint32_t* __restrict__ xw,
                              const uint32_t* __restrict__ qw,
                              int* __restrict__ flags) {
    if (blockIdx.x | threadIdx.x) return;
    bool allz = true;
    for (int i = 0; i < 64; ++i) allz = allz && ((xw[i] & 0x1FFFu) == 0u);
    int mode;
    if (allz) mode = 0;
    else {
        const u16* xh = (const u16*)xw;
        int tiny = 0;
        for (int i = 0; i < 256; ++i) {
            u16 mag = xh[i] & 0x7FFF;
            if (mag != 0 && (mag >> 7) < 118) ++tiny;
        }
        mode = (tiny >= 16) ? 2 : 1;
    }
    bool bytes = false;
    for (int i = 0; i < 64; ++i) bytes = bytes || (qw[i] > 255u);
    flags[0] = mode;
    flags[1] = bytes ? 0 : 1;
}

// ---------------- q4_0 decode ----------------
__device__ __forceinline__ void fetch18(const uint8_t* __restrict__ qraw, int qm,
                                        size_t blk, uint32_t b[18]) {
    if (qm == 0) {
        const uint8_t* p = qraw + blk * 18;
        #pragma unroll
        for (int i = 0; i < 18; ++i) b[i] = p[i];
    } else {
        const int* p = (const int*)qraw + blk * 18;
        #pragma unroll
        for (int i = 0; i < 18; ++i) b[i] = ((uint32_t)p[i]) & 0xFFu;
    }
}
__device__ __forceinline__ void decode32(const uint32_t b[18], u16 o[32]) {
    const float d = h2f((u16)(b[0] | (b[1] << 8)));
    #pragma unroll
    for (int i = 0; i < 16; ++i) {
        o[i]      = f2bf(d * (float)((int)(b[2 + i] & 15u) - 8));
        o[16 + i] = f2bf(d * (float)((int)(b[2 + i] >> 4) - 8));
    }
}

__global__ __launch_bounds__(256) void dequant_kernel(const uint8_t* __restrict__ qraw,
                                                      u16* __restrict__ W, int nblocks,
                                                      const int* __restrict__ flags) {
    const int qm = flags[1];
    const int t = blockIdx.x * 256 + threadIdx.x;
    if (t >= nblocks) return;
    uint32_t b[18];
    fetch18(qraw, qm, (size_t)t, b);
    union { u16 h[32]; uint4 v[4]; } o;
    decode32(b, o.h);
    uint4* dst = (uint4*)(W + (size_t)t * 32);
    dst[0] = o.v[0]; dst[1] = o.v[1]; dst[2] = o.v[2]; dst[3] = o.v[3];
}

// ---------------- x -> bf16 ----------------
__global__ __launch_bounds__(256) void convertx_kernel(const void* __restrict__ x,
                                                       u16* __restrict__ X, size_t n8,
                                                       const int* __restrict__ flags) {
    const int mode = flags[0];
    if (mode == 1) return;
    const size_t t = (size_t)blockIdx.x * 256 + threadIdx.x;
    if (t >= n8) return;
    union { u16 h[8]; uint4 v; } o;
    if (mode == 0) {
        const float4* xf = (const float4*)x;
        float4 a = xf[2 * t], b = xf[2 * t + 1];
        o.h[0] = f2bf(a.x); o.h[1] = f2bf(a.y); o.h[2] = f2bf(a.z); o.h[3] = f2bf(a.w);
        o.h[4] = f2bf(b.x); o.h[5] = f2bf(b.y); o.h[6] = f2bf(b.z); o.h[7] = f2bf(b.w);
    } else {
        uint4 v = ((const uint4*)x)[t];
        const u16* hh = (const u16*)&v;
        #pragma unroll
        for (int i = 0; i < 8; ++i) o.h[i] = f2bf(h2f(hh[i]));
    }
    ((uint4*)X)[t] = o.v;
}

// ---------------- epilogue helpers ----------------
__device__ __forceinline__ float load_bias(const void* bias, int col, int mode) {
    if (mode == 0) return ((const float*)bias)[col];
    u16 b = ((const u16*)bias)[col];
    return (mode == 1) ? bf2f(b) : h2f(b);
}
__device__ __forceinline__ void store_out(void* out, size_t idx, float v, int mode) {
    if (mode == 0)      ((float*)out)[idx] = v;
    else if (mode == 1) ((u16*)out)[idx] = f2bf(v);
    else                ((u16*)out)[idx] = f2h(v);
}

// ---------------- 256x256 GEMM, 16x16x32 MFMA, m201-faithful 4-phase K-tile ----------------
// LDS (u16): A(buf,half) at (buf*2+half)*8192 ; B at 32768 + (buf*2+half)*8192.
// Swizzle: LDS[row][col ^ 8*(row&7)] on both stage (pre-swizzled global src) and read.
// Phase p: { ds_reads_p ; stage? ; BAR ; lgkm(0) ; prio1 ; 16 MFMA (one quadrant) ; prio0 ; BAR }
//   p0: reads A-R01(8)+B-C0(4) [lgkm(8) hint], MFMA R01xC0
//   p1: reads B-C1(4), stage B0(t+2),          MFMA R01xC1
//   p2: reads A-R23(8), stage B1(t+2),         MFMA R23xC0
//   p3: stage A0+A1(t+2),                      MFMA R23xC1, vmcnt(8), BAR
// vmcnt(8) retires tile t-1's 8 stages -> buf(t+1) complete before next p0 reads.
__device__ __forceinline__ void stage_half(const u16* __restrict__ G, int row0, int k0,
                                           int kstride, u16* dstreg, int tid) {
    const int l = tid & 63, w = tid >> 6;
    const int r = w * 8 + (l >> 3);
    const int c = ((l & 7) * 8) ^ (((l >> 3) & 7) * 8);   // col ^ 8*(row&7)
    #pragma unroll
    for (int ch = 0; ch < 2; ++ch) {
        const u16* src = G + (size_t)(row0 + ch * 64 + r) * kstride + (k0 + c);
        u16* dst = dstreg + ch * 4096 + w * 512;     // wave-uniform; HW adds lane*16B
        __builtin_amdgcn_global_load_lds(
            (const __attribute__((address_space(1))) uint32_t*)src,
            (__attribute__((address_space(3))) uint32_t*)dst, 16, 0, 0);
    }
}

#define SCH0 __builtin_amdgcn_sched_barrier(0)

#define RD_A2(SET, BASE, HM)                                                            \
    _Pragma("unroll")                                                                   \
    for (int k = 0; k < 2; ++k)                                                         \
        _Pragma("unroll")                                                               \
        for (int i = 0; i < 4; ++i)                                                     \
            SET[k][i] = *(const bf16x8*)&lds[(BASE) + ((HM)*64 + i*16 + lm)*64 + (k ? cc1 : cc0)];

#define RD_B2(SET, BASE, HN)                                                            \
    _Pragma("unroll")                                                                   \
    for (int k = 0; k < 2; ++k)                                                         \
        _Pragma("unroll")                                                               \
        for (int j = 0; j < 2; ++j)                                                     \
            SET[k][j] = *(const bf16x8*)&lds[(BASE) + (bh + (HN)*32 + j*16 + lm)*64 + (k ? cc1 : cc0)];

#define MFMA16(ASET, BSET, R, C)                                                        \
    _Pragma("unroll")                                                                   \
    for (int i = 0; i < 4; ++i)                                                         \
        _Pragma("unroll")                                                               \
        for (int j = 0; j < 2; ++j) {                                                   \
            acc[(R)+i][(C)+j] = __builtin_amdgcn_mfma_f32_16x16x32_bf16(                \
                ASET[0][i], BSET[0][j], acc[(R)+i][(C)+j], 0, 0, 0);                    \
            acc[(R)+i][(C)+j] = __builtin_amdgcn_mfma_f32_16x16x32_bf16(                \
                ASET[1][i], BSET[1][j], acc[(R)+i][(C)+j], 0, 0, 0);                    \
        }

#define PH_MID      __builtin_amdgcn_s_barrier();                                       \
                    asm volatile("s_waitcnt lgkmcnt(0)");                               \
                    SCH0;                                                               \
                    __builtin_amdgcn_s_setprio(1);

#define PH_END      __builtin_amdgcn_s_setprio(0);                                      \
                    __builtin_amdgcn_s_barrier();                                       \
                    SCH0;

#define KTILE(TT, BUF)                                                                  \
    {                                                                                   \
        const int kt2 = ((TT)+2 < nt ? (TT)+2 : nt-1) * 64;                             \
        const int aB = ((BUF)*2 + wm) * 8192;                                           \
        const int bB = 32768 + ((BUF)*2 + (wn >> 1)) * 8192;                            \
        /* p0 */                                                                        \
        RD_A2(aX, aB, 0)                                                                \
        RD_B2(bC0, bB, 0)                                                               \
        asm volatile("s_waitcnt lgkmcnt(8)");                                           \
        PH_MID  MFMA16(aX, bC0, 0, 0)  PH_END                                           \
        /* p1 */                                                                        \
        RD_B2(bC1, bB, 1)                                                               \
        stage_half(Wptr, n0,       kt2, K, lds + (32768 + ((BUF)*2)*8192), tid);        \
        PH_MID  MFMA16(aX, bC1, 0, 2)  PH_END                                           \
        /* p2 */                                                                        \
        RD_A2(aX, aB, 1)                                                                \
        stage_half(Wptr, n0 + 128, kt2, K, lds + (32768 + ((BUF)*2+1)*8192), tid);      \
        PH_MID  MFMA16(aX, bC0, 4, 0)  PH_END                                           \
        /* p3 */                                                                        \
        stage_half(Aptr, m0,       kt2, K, lds + (((BUF)*2)*8192), tid);                \
        stage_half(Aptr, m0 + 128, kt2, K, lds + (((BUF)*2+1)*8192), tid);              \
        PH_MID  MFMA16(aX, bC1, 4, 2)                                                   \
        __builtin_amdgcn_s_setprio(0);                                                  \
        asm volatile("s_waitcnt vmcnt(8)");                                             \
        __builtin_amdgcn_s_barrier();                                                   \
        SCH0;                                                                           \
    }

__global__ __launch_bounds__(512) void gemm_8ph(const u16* __restrict__ Xraw,
                                                const u16* __restrict__ Xconv,
                                                const u16* __restrict__ Wmat,
                                                const void* __restrict__ bias,
                                                void* __restrict__ out,
                                                const int* __restrict__ flags,
                                                int M, int N, int K) {
    __shared__ __align__(16) u16 lds[65536];   // 128 KiB

    const int mode = flags[0];
    const u16* Aptr = (mode == 1) ? Xraw : Xconv;
    const u16* Wptr = Wmat;

    const int tid  = threadIdx.x;
    const int lane = tid & 63;
    const int wid  = tid >> 6;
    const int wm   = wid >> 2;        // 0..1 (M)
    const int wn   = wid & 3;         // 0..3 (N)
    const int lm   = lane & 15;
    const int kg   = lane >> 4;
    const int bh   = (wn & 1) * 64;
    const int swzu = (lm & 7) * 8;                 // 8*(row&7)
    const int cc0  = (kg * 8) ^ swzu;
    const int cc1  = (32 + kg * 8) ^ swzu;

    const int gn = N / 256;
    const int b  = blockIdx.x;
    const int per = gridDim.x >> 3;
    const int sw = ((per << 3) == (int)gridDim.x) ? ((b & 7) * per + (b >> 3)) : b;
    const int m0 = (sw / gn) * 256;
    const int n0 = (sw % gn) * 256;

    const int nt = K >> 6;

    bf16x8 aX[2][4];          // A half currently in play (refilled p0/p2)
    bf16x8 bC0[2][2], bC1[2][2];  // B col-halves, resident per K-tile
    f32x4 acc[8][4] = {};

    // prologue: stage tiles 0 (buf0) and 1 (buf1) fully; gate buf0; barrier
    stage_half(Aptr, m0,       0,  K, lds + 0,                tid);
    stage_half(Aptr, m0 + 128, 0,  K, lds + 8192,             tid);
    stage_half(Wptr, n0,       0,  K, lds + 32768,            tid);
    stage_half(Wptr, n0 + 128, 0,  K, lds + 32768 + 8192,     tid);
    stage_half(Aptr, m0,       64, K, lds + 2 * 8192,         tid);
    stage_half(Aptr, m0 + 128, 64, K, lds + 3 * 8192,         tid);
    stage_half(Wptr, n0,       64, K, lds + 32768 + 2 * 8192, tid);
    stage_half(Wptr, n0 + 128, 64, K, lds + 32768 + 3 * 8192, tid);
    asm volatile("s_waitcnt vmcnt(8)");   // tile0's 8 loads retired
    __builtin_amdgcn_s_barrier();
    SCH0;

    for (int t = 0; t < nt; t += 2) {
        KTILE(t, 0)
        KTILE(t + 1, 1)
    }

    // ---- coalesced epilogue: per-wave LDS transpose, compiler-scheduled ----
    asm volatile("s_waitcnt vmcnt(0)" ::: "memory");   // stale clamped prefetches drained
    __syncthreads();                                   // all waves' K-loop LDS reads done
    float* fl = (float*)lds;
    const int wb   = wid * 1056;                 // 16 rows x 66 floats per wave (conflict-free)
    const int rr4  = (lane >> 4) * 4;
    const int ocol = n0 + wn * 64 + lane;
    const float bvf = load_bias(bias, ocol, mode);
    #pragma unroll
    for (int i = 0; i < 8; ++i) {
        #pragma unroll
        for (int j = 0; j < 4; ++j)
            #pragma unroll
            for (int r = 0; r < 4; ++r)
                fl[wb + (rr4 + r) * 66 + j * 16 + lm] = acc[i][j][r];
        float vals[16];
        #pragma unroll
        for (int rr = 0; rr < 16; ++rr)
            vals[rr] = fl[wb + rr * 66 + lane];
        #pragma unroll
        for (int rr = 0; rr < 16; ++rr) {
            const int row = m0 + wm * 128 + i * 16 + rr;
            store_out(out, (size_t)row * N + ocol, vals[rr] + bvf, mode);
        }
    }
}

// ---------------- fallback (tiny ws): fused 128-tile ----------------
__global__ __launch_bounds__(256) void gemm_fallback(const void* __restrict__ x,
                                                     const uint8_t* __restrict__ qraw,
                                                     const void* __restrict__ bias,
                                                     void* __restrict__ out,
                                                     const int* __restrict__ flags,
                                                     int M, int N, int K, int has_flags) {
    __shared__ __align__(16) u16 lA[128 * 64];
    __shared__ __align__(16) u16 lB[128 * 64];

    const int mode = has_flags ? flags[0] : 0;
    const int qm   = has_flags ? flags[1] : 0;

    const int tid  = threadIdx.x;
    const int lane = tid & 63;
    const int wid  = tid >> 6;
    const int gn   = N / 128;

    const int b   = blockIdx.x;
    const int per = gridDim.x >> 3;
    const int sw  = ((per << 3) == (int)gridDim.x) ? ((b & 7) * per + (b >> 3)) : b;
    const int m0  = (sw / gn) * 128;
    const int n0  = (sw % gn) * 128;

    const int wm = wid >> 1, wn = wid & 1;
    const int lm = lane & 15;
    const int kg = lane >> 4;
    const int rowQ = tid >> 1, halfQ = tid & 1;

    f32x4 acc[4][4] = {};

    for (int k0 = 0; k0 < K; k0 += 64) {
        #pragma unroll
        for (int rep = 0; rep < 4; ++rep) {
            const int c = rep * 256 + tid;
            const int row = c >> 3, col = (c & 7) * 8;
            union { u16 h[8]; uint4 v; } o;
            if (mode == 0) {
                const float4* xf = (const float4*)x + ((size_t)(m0 + row) * K + k0 + col) / 4;
                float4 a = xf[0], b2 = xf[1];
                o.h[0] = f2bf(a.x);  o.h[1] = f2bf(a.y);  o.h[2] = f2bf(a.z);  o.h[3] = f2bf(a.w);
                o.h[4] = f2bf(b2.x); o.h[5] = f2bf(b2.y); o.h[6] = f2bf(b2.z); o.h[7] = f2bf(b2.w);
            } else {
                uint4 v = *(const uint4*)((const u16*)x + (size_t)(m0 + row) * K + k0 + col);
                if (mode == 1) o.v = v;
                else {
                    const u16* hh = (const u16*)&v;
                    #pragma unroll
                    for (int i = 0; i < 8; ++i) o.h[i] = f2bf(h2f(hh[i]));
                }
            }
            *(uint4*)&lA[row * 64 + col] = o.v;
        }
        {
            const size_t blk = (size_t)(n0 + rowQ) * (K >> 5) + (k0 >> 5) + halfQ;
            uint32_t bb[18];
            fetch18(qraw, qm, blk, bb);
            union { u16 h[32]; uint4 v[4]; } o;
            decode32(bb, o.h);
            uint4* dst = (uint4*)&lB[rowQ * 64 + halfQ * 32];
            dst[0] = o.v[0]; dst[1] = o.v[1]; dst[2] = o.v[2]; dst[3] = o.v[3];
        }
        __syncthreads();

        #pragma unroll
        for (int kk = 0; kk < 2; ++kk) {
            bf16x8 av[4], bv[4];
            #pragma unroll
            for (int i = 0; i < 4; ++i) {
                av[i] = *(const bf16x8*)&lA[(wm * 64 + i * 16 + lm) * 64 + kk * 32 + kg * 8];
                bv[i] = *(const bf16x8*)&lB[(wn * 64 + i * 16 + lm) * 64 + kk * 32 + kg * 8];
            }
            #pragma unroll
            for (int i = 0; i < 4; ++i)
                #pragma unroll
                for (int j = 0; j < 4; ++j)
                    acc[i][j] = __builtin_amdgcn_mfma_f32_16x16x32_bf16(av[i], bv[j], acc[i][j], 0, 0, 0);
        }
        __syncthreads();
    }

    const int rg = (lane >> 4) * 4;
    #pragma unroll
    for (int j = 0; j < 4; ++j) {
        const int col = n0 + wn * 64 + j * 16 + lm;
        const float bvf = load_bias(bias, col, mode);
        #pragma unroll
        for (int i = 0; i < 4; ++i) {
            const int row = m0 + wm * 64 + i * 16 + rg;
            #pragma unroll
            for (int r = 0; r < 4; ++r)
                store_out(out, (size_t)(row + r) * N + col, acc[i][j][r] + bvf, mode);
        }
    }
}

extern "C" void kernel_launch(void* const* d_in, const int* in_sizes, int n_in,
                              void* d_out, int out_size, void* d_ws, size_t ws_size,
                              hipStream_t stream) {
    const void*    x    = d_in[0];
    const uint8_t* qw   = (const uint8_t*)d_in[1];
    const void*    bias = d_in[2];

    const int N = in_sizes[2];
    const int row_elems = in_sizes[1] / N;
    const int K = (row_elems / 18) * 32;
    const int M = in_sizes[0] / K;

    const size_t offW = 256;
    const size_t offX = offW + (size_t)N * K * 2;
    const size_t need = offX + (size_t)M * K * 2;

    const int nt = K >> 6;
    const bool big_ok = (M % 256 == 0) && (N % 256 == 0) && (nt >= 4) && ((nt & 1) == 0);

    if (ws_size >= need && big_ok) {
        int* flags = (int*)d_ws;
        u16* W = (u16*)((char*)d_ws + offW);
        u16* X = (u16*)((char*)d_ws + offX);
        detect_kernel<<<1, 64, 0, stream>>>((const uint32_t*)x, (const uint32_t*)qw, flags);
        const int nblocks = N * (K >> 5);
        dequant_kernel<<<(nblocks + 255) / 256, 256, 0, stream>>>(qw, W, nblocks, flags);
        const size_t n8 = (size_t)M * K / 8;
        convertx_kernel<<<(int)((n8 + 255) / 256), 256, 0, stream>>>(x, X, n8, flags);
        gemm_8ph<<<(M / 256) * (N / 256), 512, 0, stream>>>((const u16*)x, X, W, bias,
                                                            d_out, flags, M, N, K);
    } else if (ws_size >= 16) {
        int* flags = (int*)d_ws;
        detect_kernel<<<1, 64, 0, stream>>>((const uint32_t*)x, (const uint32_t*)qw, flags);
        gemm_fallback<<<(M / 128) * (N / 128), 256, 0, stream>>>(x, qw, bias, d_out, flags, M, N, K, 1);
    } else {
        gemm_fallback<<<(M / 128) * (N / 128), 256, 0, stream>>>(x, qw, bias, d_out, nullptr, M, N, K, 0);
    }
}

// Round 10
// 285.931 us; speedup vs baseline: 1.1714x; 1.1714x over previous
//
#include <hip/hip_runtime.h>
#include <stdint.h>

typedef unsigned short u16;
typedef __attribute__((ext_vector_type(8))) __bf16 bf16x8;
typedef __attribute__((ext_vector_type(4))) float f32x4;

// ---------------- scalar helpers ----------------
__device__ __forceinline__ u16 f2bf(float f) {
    uint32_t u = __float_as_uint(f);
    u += 0x7FFF + ((u >> 16) & 1);   // RNE
    return (u16)(u >> 16);
}
__device__ __forceinline__ float bf2f(u16 b) {
    return __uint_as_float(((uint32_t)b) << 16);
}
__device__ __forceinline__ float h2f(u16 h) {
    float r; uint32_t x = h;
    asm volatile("v_cvt_f32_f16_e32 %0, %1" : "=v"(r) : "v"(x));
    return r;
}
__device__ __forceinline__ u16 f2h(float f) {
    uint32_t r;
    asm volatile("v_cvt_f16_f32_e32 %0, %1" : "=v"(r) : "v"(f));
    return (u16)r;
}

// ---------------- dtype detection ----------------
// flags[0]: x/bias/out mode: 0=float32, 1=bf16(u16), 2=fp16(u16)
// flags[1]: qweight mode:    0=packed bytes, 1=one byte per int32
__global__ void detect_kernel(const uint32_t* __restrict__ xw,
                              const uint32_t* __restrict__ qw,
                              int* __restrict__ flags) {
    if (blockIdx.x | threadIdx.x) return;
    bool allz = true;
    for (int i = 0; i < 64; ++i) allz = allz && ((xw[i] & 0x1FFFu) == 0u);
    int mode;
    if (allz) mode = 0;
    else {
        const u16* xh = (const u16*)xw;
        int tiny = 0;
        for (int i = 0; i < 256; ++i) {
            u16 mag = xh[i] & 0x7FFF;
            if (mag != 0 && (mag >> 7) < 118) ++tiny;
        }
        mode = (tiny >= 16) ? 2 : 1;
    }
    bool bytes = false;
    for (int i = 0; i < 64; ++i) bytes = bytes || (qw[i] > 255u);
    flags[0] = mode;
    flags[1] = bytes ? 0 : 1;
}

// ---------------- q4_0 dequant (vectorized fetch) ----------------
__global__ __launch_bounds__(256) void dequant_kernel(const uint8_t* __restrict__ qraw,
                                                      u16* __restrict__ W, int nblocks,
                                                      const int* __restrict__ flags) {
    const int qm = flags[1];
    const int t = blockIdx.x * 256 + threadIdx.x;
    if (t >= nblocks) return;
    float d;
    uint32_t qsw[4];
    if (qm == 0) {
        const uint8_t* p = qraw + (size_t)t * 18;
        if (t & 1) {                         // byte offset ≡ 2 (mod 4)
            d = h2f(*(const u16*)p);
            const uint4 q = *(const uint4*)(p + 2);   // 4-aligned
            qsw[0] = q.x; qsw[1] = q.y; qsw[2] = q.z; qsw[3] = q.w;
        } else {                             // 4-aligned block start
            const uint32_t* pw = (const uint32_t*)p;
            const uint32_t d0 = pw[0], d1 = pw[1], d2 = pw[2], d3 = pw[3];
            const uint32_t d4 = (t + 1 < nblocks) ? pw[4]
                                                  : (uint32_t)*(const u16*)(p + 16);
            d = h2f((u16)(d0 & 0xFFFF));
            qsw[0] = (d0 >> 16) | (d1 << 16);
            qsw[1] = (d1 >> 16) | (d2 << 16);
            qsw[2] = (d2 >> 16) | (d3 << 16);
            qsw[3] = (d3 >> 16) | (d4 << 16);
        }
    } else {                                 // one byte per int32
        const int* p = (const int*)qraw + (size_t)t * 18;
        uint32_t b[18];
        #pragma unroll
        for (int i = 0; i < 18; ++i) b[i] = ((uint32_t)p[i]) & 0xFFu;
        d = h2f((u16)(b[0] | (b[1] << 8)));
        #pragma unroll
        for (int k = 0; k < 4; ++k)
            qsw[k] = b[2 + 4 * k] | (b[3 + 4 * k] << 8) | (b[4 + 4 * k] << 16) | (b[5 + 4 * k] << 24);
    }
    union { u16 h[32]; uint4 v[4]; } o;
    #pragma unroll
    for (int i = 0; i < 16; ++i) {
        const uint32_t byte = (qsw[i >> 2] >> ((i & 3) * 8)) & 0xFFu;
        o.h[i]      = f2bf(d * (float)((int)(byte & 15u) - 8));
        o.h[16 + i] = f2bf(d * (float)((int)(byte >> 4) - 8));
    }
    uint4* dst = (uint4*)(W + (size_t)t * 32);
    dst[0] = o.v[0]; dst[1] = o.v[1]; dst[2] = o.v[2]; dst[3] = o.v[3];
}

// ---------------- x -> bf16 ----------------
__global__ __launch_bounds__(256) void convertx_kernel(const void* __restrict__ x,
                                                       u16* __restrict__ X, size_t n8,
                                                       const int* __restrict__ flags) {
    const int mode = flags[0];
    if (mode == 1) return;
    const size_t t = (size_t)blockIdx.x * 256 + threadIdx.x;
    if (t >= n8) return;
    union { u16 h[8]; uint4 v; } o;
    if (mode == 0) {
        const float4* xf = (const float4*)x;
        float4 a = xf[2 * t], b = xf[2 * t + 1];
        o.h[0] = f2bf(a.x); o.h[1] = f2bf(a.y); o.h[2] = f2bf(a.z); o.h[3] = f2bf(a.w);
        o.h[4] = f2bf(b.x); o.h[5] = f2bf(b.y); o.h[6] = f2bf(b.z); o.h[7] = f2bf(b.w);
    } else {
        uint4 v = ((const uint4*)x)[t];
        const u16* hh = (const u16*)&v;
        #pragma unroll
        for (int i = 0; i < 8; ++i) o.h[i] = f2bf(h2f(hh[i]));
    }
    ((uint4*)X)[t] = o.v;
}

// ---------------- epilogue helpers ----------------
__device__ __forceinline__ float load_bias(const void* bias, int col, int mode) {
    if (mode == 0) return ((const float*)bias)[col];
    u16 b = ((const u16*)bias)[col];
    return (mode == 1) ? bf2f(b) : h2f(b);
}
__device__ __forceinline__ void store_out(void* out, size_t idx, float v, int mode) {
    if (mode == 0)      ((float*)out)[idx] = v;
    else if (mode == 1) ((u16*)out)[idx] = f2bf(v);
    else                ((u16*)out)[idx] = f2h(v);
}

// ---------------- 256x256 8-subphase pipelined GEMM (r7 skeleton, 8 barriers/K-tile) ----------------
// LDS (u16): A(buf,half) at (buf*2+half)*8192 ; B at 32768 + (buf*2+half)*8192.
// Swizzle: LDS[row][col ^ 8*(row&7)], both staged (global src pre-swizzled) and read.
// Region-write safety (mid-barriers only): a write at phase p+2's pre-mid section is
// safe when the region's last read-issue was phase p and the reads drain at p+1's
// counted lgkm (passing p+1's mid-barrier implies all waves executed p's lgkm).
//   B-region (bB): last read s0 (b11), drained s1 lgkm(0)  -> B-stage at s3. 
//   A-region (aB): last read s4 (a1), drained s5 lgkm(2)   -> A-stage at s7.
// vmcnt(4) pre-mid at s4 retires tile(t-1)'s 8 gloads -> buf^1 ready for s5+ reads.
__device__ __forceinline__ void stage_half(const u16* __restrict__ G, int row0, int k0,
                                           int kstride, u16* dstreg, int tid) {
    const int l = tid & 63, w = tid >> 6;
    const int r = w * 8 + (l >> 3);
    const int c = ((l & 7) * 8) ^ (((l >> 3) & 7) * 8);   // col ^ 8*(row&7)
    #pragma unroll
    for (int ch = 0; ch < 2; ++ch) {
        const u16* src = G + (size_t)(row0 + ch * 64 + r) * kstride + (k0 + c);
        u16* dst = dstreg + ch * 4096 + w * 512;     // wave-uniform; HW adds lane*16B
        __builtin_amdgcn_global_load_lds(
            (const __attribute__((address_space(1))) uint32_t*)src,
            (__attribute__((address_space(3))) uint32_t*)dst, 16, 0, 0);
    }
}

#define SEG_MID(N)  __builtin_amdgcn_s_barrier();                      \
                    asm volatile("s_waitcnt lgkmcnt(" #N ")");         \
                    __builtin_amdgcn_sched_barrier(0);                 \
                    __builtin_amdgcn_s_setprio(1);

#define SEG_CUT     __builtin_amdgcn_s_setprio(0);                     \
                    __builtin_amdgcn_sched_barrier(0);

#define RD_A(DST, BASE, HM, KK)                                                         \
    _Pragma("unroll")                                                                   \
    for (int i = 0; i < 4; ++i)                                                         \
        DST[i] = *(const bf16x8*)&lds[(BASE) + ((HM)*64 + i*16 + lm)*64 + ((KK) ? cc1 : cc0)];

#define RD_B(DST, BASE, HN, KK)                                                         \
    _Pragma("unroll")                                                                   \
    for (int j = 0; j < 2; ++j)                                                         \
        DST[j] = *(const bf16x8*)&lds[(BASE) + (bh + (HN)*32 + j*16 + lm)*64 + ((KK) ? cc1 : cc0)];

#define MFMA8(ASET, BSET, R, C)                                                         \
    _Pragma("unroll")                                                                   \
    for (int i = 0; i < 4; ++i)                                                         \
        _Pragma("unroll")                                                               \
        for (int j = 0; j < 2; ++j)                                                     \
            acc[(R)+i][(C)+j] = __builtin_amdgcn_mfma_f32_16x16x32_bf16(                \
                ASET[i], BSET[j], acc[(R)+i][(C)+j], 0, 0, 0);

// lgkm ledger (per wave, ds_reads only): enter s0 with 6 (prev s7's b10+a0).
// s0:+6 lgkm(6) | s1:+0 lgkm(0) | s2:+0 lgkm(6)=free | s3:+4 lgkm(4) | s4:+4 lgkm(4)
// s5:+2 lgkm(2) | s6:+2 lgkm(4)=free | s7:+6 lgkm(6) -> steady 6.
#define KTILE(TT, BUF)                                                                  \
    {                                                                                   \
        const int kt2 = ((TT)+2 < nt ? (TT)+2 : nt-1) * 64;                             \
        const int aB  = ((BUF)*2 + wm) * 8192;                                          \
        const int bB  = 32768 + ((BUF)*2 + (wn >> 1)) * 8192;                           \
        const int aBo = (((BUF)^1)*2 + wm) * 8192;                                      \
        const int bBo = 32768 + (((BUF)^1)*2 + (wn >> 1)) * 8192;                       \
        /* s0: (0,0,k0) */                                                              \
        RD_A(a1, aB, 0, 1) RD_B(b11, bB, 1, 1)                                          \
        SEG_MID(6)  MFMA8(a0, b00, 0, 0)  SEG_CUT                                       \
        /* s1: (0,0,k1) */                                                              \
        SEG_MID(0)  MFMA8(a1, b01, 0, 0)  SEG_CUT                                       \
        /* s2: (0,1,k0) */                                                              \
        SEG_MID(6)  MFMA8(a0, b10, 0, 2)  SEG_CUT                                       \
        /* s3: (0,1,k1) + stage B(t+2) [bB reads drained at s1 lgkm(0)] */              \
        RD_A(a0, aB, 1, 0)                                                              \
        stage_half(Wptr, n0,       kt2, K, lds + (32768 + ((BUF)*2)*8192), tid);        \
        stage_half(Wptr, n0 + 128, kt2, K, lds + (32768 + ((BUF)*2+1)*8192), tid);      \
        SEG_MID(4)  MFMA8(a1, b11, 0, 2)  SEG_CUT                                       \
        /* s4: (1,0,k0) + vmcnt gate pre-barrier (t-1's 8 gloads retired) */            \
        RD_A(a1, aB, 1, 1)                                                              \
        asm volatile("s_waitcnt vmcnt(4)" ::: "memory");                                \
        SEG_MID(4)  MFMA8(a0, b00, 4, 0)  SEG_CUT                                       \
        /* s5: (1,0,k1) */                                                              \
        RD_B(b00, bBo, 0, 0)                                                            \
        SEG_MID(2)  MFMA8(a1, b01, 4, 0)  SEG_CUT                                       \
        /* s6: (1,1,k0) */                                                              \
        RD_B(b01, bBo, 0, 1)                                                            \
        SEG_MID(4)  MFMA8(a0, b10, 4, 2)  SEG_CUT                                       \
        /* s7: (1,1,k1) + stage A(t+2) [aB reads drained at s5 lgkm(2)] */              \
        RD_B(b10, bBo, 1, 0) RD_A(a0, aBo, 0, 0)                                        \
        stage_half(Aptr, m0,       kt2, K, lds + (((BUF)*2)*8192), tid);                \
        stage_half(Aptr, m0 + 128, kt2, K, lds + (((BUF)*2+1)*8192), tid);              \
        SEG_MID(6)  MFMA8(a1, b11, 4, 2)  SEG_CUT                                       \
    }

__global__ __launch_bounds__(512) void gemm_8ph(const u16* __restrict__ Xraw,
                                                const u16* __restrict__ Xconv,
                                                const u16* __restrict__ Wmat,
                                                const void* __restrict__ bias,
                                                void* __restrict__ out,
                                                const int* __restrict__ flags,
                                                int M, int N, int K) {
    __shared__ __align__(16) u16 lds[65536];   // 128 KiB

    const int mode = flags[0];
    const u16* Aptr = (mode == 1) ? Xraw : Xconv;
    const u16* Wptr = Wmat;

    const int tid  = threadIdx.x;
    const int lane = tid & 63;
    const int wid  = tid >> 6;
    const int wm   = wid >> 2;        // 0..1 (M)
    const int wn   = wid & 3;         // 0..3 (N)
    const int lm   = lane & 15;
    const int kg   = lane >> 4;
    const int bh   = (wn & 1) * 64;
    const int swzu = (lm & 7) * 8;                 // 8*(row&7)
    const int cc0  = (kg * 8) ^ swzu;
    const int cc1  = (32 + kg * 8) ^ swzu;

    const int gn = N / 256;
    const int b  = blockIdx.x;
    const int per = gridDim.x >> 3;
    const int sw = ((per << 3) == (int)gridDim.x) ? ((b & 7) * per + (b >> 3)) : b;
    const int m0 = (sw / gn) * 256;
    const int n0 = (sw % gn) * 256;

    const int nt = K >> 6;

    bf16x8 a0[4], a1[4];
    bf16x8 b00[2], b01[2], b10[2], b11[2];
    f32x4 acc[8][4] = {};

    // prologue: stage tiles 0 and 1 fully (16 gloads), retire tile0's, pre-read s0 operands
    stage_half(Aptr, m0,       0,  K, lds + 0,                tid);
    stage_half(Aptr, m0 + 128, 0,  K, lds + 8192,             tid);
    stage_half(Wptr, n0,       0,  K, lds + 32768,            tid);
    stage_half(Wptr, n0 + 128, 0,  K, lds + 32768 + 8192,     tid);
    stage_half(Aptr, m0,       64, K, lds + 2 * 8192,         tid);
    stage_half(Aptr, m0 + 128, 64, K, lds + 3 * 8192,         tid);
    stage_half(Wptr, n0,       64, K, lds + 32768 + 2 * 8192, tid);
    stage_half(Wptr, n0 + 128, 64, K, lds + 32768 + 3 * 8192, tid);
    asm volatile("s_waitcnt vmcnt(8)" ::: "memory");
    __builtin_amdgcn_s_barrier();
    __builtin_amdgcn_sched_barrier(0);
    // pre-reads for tile0 s0: b00,b01,b10,a0 from buf0 (drained by s0's lgkm(6))
    {
        const int aB = wm * 8192;
        const int bB = 32768 + (wn >> 1) * 8192;
        RD_B(b00, bB, 0, 0)
        RD_B(b01, bB, 0, 1)
        RD_B(b10, bB, 1, 0)
        RD_A(a0,  aB, 0, 0)
    }
    __builtin_amdgcn_sched_barrier(0);

    for (int t = 0; t < nt; t += 2) {
        KTILE(t, 0)
        KTILE(t + 1, 1)
    }

    // ---- coalesced epilogue: per-wave LDS transpose, compiler-scheduled ----
    asm volatile("s_waitcnt vmcnt(0)" ::: "memory");   // stale clamped prefetches drained
    __syncthreads();                                   // all waves' K-loop LDS reads done
    float* fl = (float*)lds;
    const int wb   = wid * 1056;                 // 16 rows x 66 floats per wave (conflict-free)
    const int rr4  = (lane >> 4) * 4;
    const int ocol = n0 + wn * 64 + lane;
    const float bvf = load_bias(bias, ocol, mode);
    #pragma unroll
    for (int i = 0; i < 8; ++i) {
        #pragma unroll
        for (int j = 0; j < 4; ++j)
            #pragma unroll
            for (int r = 0; r < 4; ++r)
                fl[wb + (rr4 + r) * 66 + j * 16 + lm] = acc[i][j][r];
        float vals[16];
        #pragma unroll
        for (int rr = 0; rr < 16; ++rr)
            vals[rr] = fl[wb + rr * 66 + lane];
        #pragma unroll
        for (int rr = 0; rr < 16; ++rr) {
            const int row = m0 + wm * 128 + i * 16 + rr;
            store_out(out, (size_t)row * N + ocol, vals[rr] + bvf, mode);
        }
    }
}

// ---------------- fallback (tiny ws): fused 128-tile ----------------
__global__ __launch_bounds__(256) void gemm_fallback(const void* __restrict__ x,
                                                     const uint8_t* __restrict__ qraw,
                                                     const void* __restrict__ bias,
                                                     void* __restrict__ out,
                                                     const int* __restrict__ flags,
                                                     int M, int N, int K, int has_flags) {
    __shared__ __align__(16) u16 lA[128 * 64];
    __shared__ __align__(16) u16 lB[128 * 64];

    const int mode = has_flags ? flags[0] : 0;
    const int qm   = has_flags ? flags[1] : 0;

    const int tid  = threadIdx.x;
    const int lane = tid & 63;
    const int wid  = tid >> 6;
    const int gn   = N / 128;

    const int b   = blockIdx.x;
    const int per = gridDim.x >> 3;
    const int sw  = ((per << 3) == (int)gridDim.x) ? ((b & 7) * per + (b >> 3)) : b;
    const int m0  = (sw / gn) * 128;
    const int n0  = (sw % gn) * 128;

    const int wm = wid >> 1, wn = wid & 1;
    const int lm = lane & 15;
    const int kg = lane >> 4;
    const int rowQ = tid >> 1, halfQ = tid & 1;

    f32x4 acc[4][4] = {};

    for (int k0 = 0; k0 < K; k0 += 64) {
        #pragma unroll
        for (int rep = 0; rep < 4; ++rep) {
            const int c = rep * 256 + tid;
            const int row = c >> 3, col = (c & 7) * 8;
            union { u16 h[8]; uint4 v; } o;
            if (mode == 0) {
                const float4* xf = (const float4*)x + ((size_t)(m0 + row) * K + k0 + col) / 4;
                float4 a = xf[0], b2 = xf[1];
                o.h[0] = f2bf(a.x);  o.h[1] = f2bf(a.y);  o.h[2] = f2bf(a.z);  o.h[3] = f2bf(a.w);
                o.h[4] = f2bf(b2.x); o.h[5] = f2bf(b2.y); o.h[6] = f2bf(b2.z); o.h[7] = f2bf(b2.w);
            } else {
                uint4 v = *(const uint4*)((const u16*)x + (size_t)(m0 + row) * K + k0 + col);
                if (mode == 1) o.v = v;
                else {
                    const u16* hh = (const u16*)&v;
                    #pragma unroll
                    for (int i = 0; i < 8; ++i) o.h[i] = f2bf(h2f(hh[i]));
                }
            }
            *(uint4*)&lA[row * 64 + col] = o.v;
        }
        {
            const size_t blk = (size_t)(n0 + rowQ) * (K >> 5) + (k0 >> 5) + halfQ;
            uint32_t bb[18];
            if (qm == 0) {
                const uint8_t* p = qraw + blk * 18;
                #pragma unroll
                for (int i = 0; i < 18; ++i) bb[i] = p[i];
            } else {
                const int* p = (const int*)qraw + blk * 18;
                #pragma unroll
                for (int i = 0; i < 18; ++i) bb[i] = ((uint32_t)p[i]) & 0xFFu;
            }
            const float d = h2f((u16)(bb[0] | (bb[1] << 8)));
            union { u16 h[32]; uint4 v[4]; } o;
            #pragma unroll
            for (int i = 0; i < 16; ++i) {
                o.h[i]      = f2bf(d * (float)((int)(bb[2 + i] & 15u) - 8));
                o.h[16 + i] = f2bf(d * (float)((int)(bb[2 + i] >> 4) - 8));
            }
            uint4* dst = (uint4*)&lB[rowQ * 64 + halfQ * 32];
            dst[0] = o.v[0]; dst[1] = o.v[1]; dst[2] = o.v[2]; dst[3] = o.v[3];
        }
        __syncthreads();

        #pragma unroll
        for (int kk = 0; kk < 2; ++kk) {
            bf16x8 av[4], bv[4];
            #pragma unroll
            for (int i = 0; i < 4; ++i) {
                av[i] = *(const bf16x8*)&lA[(wm * 64 + i * 16 + lm) * 64 + kk * 32 + kg * 8];
                bv[i] = *(const bf16x8*)&lB[(wn * 64 + i * 16 + lm) * 64 + kk * 32 + kg * 8];
            }
            #pragma unroll
            for (int i = 0; i < 4; ++i)
                #pragma unroll
                for (int j = 0; j < 4; ++j)
                    acc[i][j] = __builtin_amdgcn_mfma_f32_16x16x32_bf16(av[i], bv[j], acc[i][j], 0, 0, 0);
        }
        __syncthreads();
    }

    const int rg = (lane >> 4) * 4;
    #pragma unroll
    for (int j = 0; j < 4; ++j) {
        const int col = n0 + wn * 64 + j * 16 + lm;
        const float bvf = load_bias(bias, col, mode);
        #pragma unroll
        for (int i = 0; i < 4; ++i) {
            const int row = m0 + wm * 64 + i * 16 + rg;
            #pragma unroll
            for (int r = 0; r < 4; ++r)
                store_out(out, (size_t)(row + r) * N + col, acc[i][j][r] + bvf, mode);
        }
    }
}

extern "C" void kernel_launch(void* const* d_in, const int* in_sizes, int n_in,
                              void* d_out, int out_size, void* d_ws, size_t ws_size,
                              hipStream_t stream) {
    const void*    x    = d_in[0];
    const uint8_t* qw   = (const uint8_t*)d_in[1];
    const void*    bias = d_in[2];

    const int N = in_sizes[2];
    const int row_elems = in_sizes[1] / N;
    const int K = (row_elems / 18) * 32;
    const int M = in_sizes[0] / K;

    const size_t offW = 256;
    const size_t offX = offW + (size_t)N * K * 2;
    const size_t need = offX + (size_t)M * K * 2;

    const int nt = K >> 6;
    const bool big_ok = (M % 256 == 0) && (N % 256 == 0) && (nt >= 4) && ((nt & 1) == 0);

    if (ws_size >= need && big_ok) {
        int* flags = (int*)d_ws;
        u16* W = (u16*)((char*)d_ws + offW);
        u16* X = (u16*)((char*)d_ws + offX);
        detect_kernel<<<1, 64, 0, stream>>>((const uint32_t*)x, (const uint32_t*)qw, flags);
        const int nblocks = N * (K >> 5);
        dequant_kernel<<<(nblocks + 255) / 256, 256, 0, stream>>>(qw, W, nblocks, flags);
        const size_t n8 = (size_t)M * K / 8;
        convertx_kernel<<<(int)((n8 + 255) / 256), 256, 0, stream>>>(x, X, n8, flags);
        gemm_8ph<<<(M / 256) * (N / 256), 512, 0, stream>>>((const u16*)x, X, W, bias,
                                                            d_out, flags, M, N, K);
    } else if (ws_size >= 16) {
        int* flags = (int*)d_ws;
        detect_kernel<<<1, 64, 0, stream>>>((const uint32_t*)x, (const uint32_t*)qw, flags);
        gemm_fallback<<<(M / 128) * (N / 128), 256, 0, stream>>>(x, qw, bias, d_out, flags, M, N, K, 1);
    } else {
        gemm_fallback<<<(M / 128) * (N / 128), 256, 0, stream>>>(x, qw, bias, d_out, nullptr, M, N, K, 0);
    }
}

// Round 11
// 278.709 us; speedup vs baseline: 1.2017x; 1.0259x over previous
//
#include <hip/hip_runtime.h>
#include <stdint.h>

typedef unsigned short u16;
typedef __attribute__((ext_vector_type(8))) __bf16 bf16x8;
typedef __attribute__((ext_vector_type(4))) float f32x4;

// ---------------- scalar helpers ----------------
__device__ __forceinline__ u16 f2bf(float f) {
    uint32_t u = __float_as_uint(f);
    u += 0x7FFF + ((u >> 16) & 1);   // RNE
    return (u16)(u >> 16);
}
__device__ __forceinline__ float bf2f(u16 b) {
    return __uint_as_float(((uint32_t)b) << 16);
}
__device__ __forceinline__ float h2f(u16 h) {
    float r; uint32_t x = h;
    asm volatile("v_cvt_f32_f16_e32 %0, %1" : "=v"(r) : "v"(x));
    return r;
}
__device__ __forceinline__ u16 f2h(float f) {
    uint32_t r;
    asm volatile("v_cvt_f16_f32_e32 %0, %1" : "=v"(r) : "v"(f));
    return (u16)r;
}

// ---------------- dtype detection ----------------
// flags[0]: x/bias/out mode: 0=float32, 1=bf16(u16), 2=fp16(u16)
// flags[1]: qweight mode:    0=packed bytes, 1=one byte per int32
__global__ void detect_kernel(const uint32_t* __restrict__ xw,
                              const uint32_t* __restrict__ qw,
                              int* __restrict__ flags) {
    if (blockIdx.x | threadIdx.x) return;
    bool allz = true;
    for (int i = 0; i < 64; ++i) allz = allz && ((xw[i] & 0x1FFFu) == 0u);
    int mode;
    if (allz) mode = 0;
    else {
        const u16* xh = (const u16*)xw;
        int tiny = 0;
        for (int i = 0; i < 256; ++i) {
            u16 mag = xh[i] & 0x7FFF;
            if (mag != 0 && (mag >> 7) < 118) ++tiny;
        }
        mode = (tiny >= 16) ? 2 : 1;
    }
    bool bytes = false;
    for (int i = 0; i < 64; ++i) bytes = bytes || (qw[i] > 255u);
    flags[0] = mode;
    flags[1] = bytes ? 0 : 1;
}

// ---------------- fused prepass: dequant (role A) + x->bf16 convert (role B) ----------------
__global__ __launch_bounds__(256) void prepass_kernel(const uint8_t* __restrict__ qraw,
                                                      const void* __restrict__ x,
                                                      u16* __restrict__ W,
                                                      u16* __restrict__ X,
                                                      int nblocks, size_t n8, int nblk_dq,
                                                      const int* __restrict__ flags) {
    if ((int)blockIdx.x < nblk_dq) {
        // ---- dequant role (vectorized fetch) ----
        const int qm = flags[1];
        const int t = blockIdx.x * 256 + threadIdx.x;
        if (t >= nblocks) return;
        float d;
        uint32_t qsw[4];
        if (qm == 0) {
            const uint8_t* p = qraw + (size_t)t * 18;
            if (t & 1) {                         // byte offset ≡ 2 (mod 4)
                d = h2f(*(const u16*)p);
                const uint4 q = *(const uint4*)(p + 2);   // 4-aligned
                qsw[0] = q.x; qsw[1] = q.y; qsw[2] = q.z; qsw[3] = q.w;
            } else {                             // 4-aligned block start
                const uint32_t* pw = (const uint32_t*)p;
                const uint32_t d0 = pw[0], d1 = pw[1], d2 = pw[2], d3 = pw[3];
                const uint32_t d4 = (t + 1 < nblocks) ? pw[4]
                                                      : (uint32_t)*(const u16*)(p + 16);
                d = h2f((u16)(d0 & 0xFFFF));
                qsw[0] = (d0 >> 16) | (d1 << 16);
                qsw[1] = (d1 >> 16) | (d2 << 16);
                qsw[2] = (d2 >> 16) | (d3 << 16);
                qsw[3] = (d3 >> 16) | (d4 << 16);
            }
        } else {                                 // one byte per int32
            const int* p = (const int*)qraw + (size_t)t * 18;
            uint32_t b[18];
            #pragma unroll
            for (int i = 0; i < 18; ++i) b[i] = ((uint32_t)p[i]) & 0xFFu;
            d = h2f((u16)(b[0] | (b[1] << 8)));
            #pragma unroll
            for (int k = 0; k < 4; ++k)
                qsw[k] = b[2 + 4 * k] | (b[3 + 4 * k] << 8) | (b[4 + 4 * k] << 16) | (b[5 + 4 * k] << 24);
        }
        union { u16 h[32]; uint4 v[4]; } o;
        #pragma unroll
        for (int i = 0; i < 16; ++i) {
            const uint32_t byte = (qsw[i >> 2] >> ((i & 3) * 8)) & 0xFFu;
            o.h[i]      = f2bf(d * (float)((int)(byte & 15u) - 8));
            o.h[16 + i] = f2bf(d * (float)((int)(byte >> 4) - 8));
        }
        uint4* dst = (uint4*)(W + (size_t)t * 32);
        dst[0] = o.v[0]; dst[1] = o.v[1]; dst[2] = o.v[2]; dst[3] = o.v[3];
    } else {
        // ---- convert role ----
        const int mode = flags[0];
        if (mode == 1) return;                   // already bf16, GEMM reads d_in[0] directly
        const size_t t = (size_t)(blockIdx.x - nblk_dq) * 256 + threadIdx.x;
        if (t >= n8) return;
        union { u16 h[8]; uint4 v; } o;
        if (mode == 0) {
            const float4* xf = (const float4*)x;
            float4 a = xf[2 * t], b = xf[2 * t + 1];
            o.h[0] = f2bf(a.x); o.h[1] = f2bf(a.y); o.h[2] = f2bf(a.z); o.h[3] = f2bf(a.w);
            o.h[4] = f2bf(b.x); o.h[5] = f2bf(b.y); o.h[6] = f2bf(b.z); o.h[7] = f2bf(b.w);
        } else {
            uint4 v = ((const uint4*)x)[t];
            const u16* hh = (const u16*)&v;
            #pragma unroll
            for (int i = 0; i < 8; ++i) o.h[i] = f2bf(h2f(hh[i]));
        }
        ((uint4*)X)[t] = o.v;
    }
}

// ---------------- epilogue helpers ----------------
__device__ __forceinline__ float load_bias(const void* bias, int col, int mode) {
    if (mode == 0) return ((const float*)bias)[col];
    u16 b = ((const u16*)bias)[col];
    return (mode == 1) ? bf2f(b) : h2f(b);
}
__device__ __forceinline__ void store_out(void* out, size_t idx, float v, int mode) {
    if (mode == 0)      ((float*)out)[idx] = v;
    else if (mode == 1) ((u16*)out)[idx] = f2bf(v);
    else                ((u16*)out)[idx] = f2h(v);
}

// ---------------- 256x256 8-subphase pipelined GEMM (r10 skeleton, stages spread) ----------------
// LDS (u16): A(buf,half) at (buf*2+half)*8192 ; B at 32768 + (buf*2+half)*8192.
// Swizzle: LDS[row][col ^ 8*(row&7)], both staged (global src pre-swizzled) and read.
// Region-write safety (mid-barriers only): a write at phase p+2's pre-mid section is
// safe when the region's last read-issue was phase p and the reads drain at p+1's
// counted lgkm (passing p+1's mid-barrier implies all waves executed p's lgkm).
//   B-region (bB): last read s0 (b11), drained s1 lgkm(0)  -> B0-stage s3, B1-stage s4.
//   A-region (aB): last read s4 (a1), drained s5 lgkm(2)   -> A-stages s7.
// vmcnt(4) pre-mid at s4 (after B1 issue): FIFO keeps B0,B1(t) -> drains
// B0B1(t-1)+A(t-1), exactly the stages feeding buf^1 reads at s5+/s7.
__device__ __forceinline__ void stage_half(const u16* __restrict__ G, int row0, int k0,
                                           int kstride, u16* dstreg, int tid) {
    const int l = tid & 63, w = tid >> 6;
    const int r = w * 8 + (l >> 3);
    const int c = ((l & 7) * 8) ^ (((l >> 3) & 7) * 8);   // col ^ 8*(row&7)
    #pragma unroll
    for (int ch = 0; ch < 2; ++ch) {
        const u16* src = G + (size_t)(row0 + ch * 64 + r) * kstride + (k0 + c);
        u16* dst = dstreg + ch * 4096 + w * 512;     // wave-uniform; HW adds lane*16B
        __builtin_amdgcn_global_load_lds(
            (const __attribute__((address_space(1))) uint32_t*)src,
            (__attribute__((address_space(3))) uint32_t*)dst, 16, 0, 0);
    }
}

#define SEG_MID(N)  __builtin_amdgcn_s_barrier();                      \
                    asm volatile("s_waitcnt lgkmcnt(" #N ")");         \
                    __builtin_amdgcn_sched_barrier(0);                 \
                    __builtin_amdgcn_s_setprio(1);

#define SEG_CUT     __builtin_amdgcn_s_setprio(0);                     \
                    __builtin_amdgcn_sched_barrier(0);

#define RD_A(DST, BASE, HM, KK)                                                         \
    _Pragma("unroll")                                                                   \
    for (int i = 0; i < 4; ++i)                                                         \
        DST[i] = *(const bf16x8*)&lds[(BASE) + ((HM)*64 + i*16 + lm)*64 + ((KK) ? cc1 : cc0)];

#define RD_B(DST, BASE, HN, KK)                                                         \
    _Pragma("unroll")                                                                   \
    for (int j = 0; j < 2; ++j)                                                         \
        DST[j] = *(const bf16x8*)&lds[(BASE) + (bh + (HN)*32 + j*16 + lm)*64 + ((KK) ? cc1 : cc0)];

#define MFMA8(ASET, BSET, R, C)                                                         \
    _Pragma("unroll")                                                                   \
    for (int i = 0; i < 4; ++i)                                                         \
        _Pragma("unroll")                                                               \
        for (int j = 0; j < 2; ++j)                                                     \
            acc[(R)+i][(C)+j] = __builtin_amdgcn_mfma_f32_16x16x32_bf16(                \
                ASET[i], BSET[j], acc[(R)+i][(C)+j], 0, 0, 0);

// lgkm ledger (ds_reads only; stages are vmcnt): enter s0 with 6 (prev s7's b10+a0).
// s0:+6 lgkm(6) | s1:+0 lgkm(0) | s2:+0 lgkm(6)=free | s3:+4 lgkm(4) | s4:+4 lgkm(4)
// s5:+2 lgkm(2) | s6:+2 lgkm(4)=free | s7:+6 lgkm(6) -> steady 6.
#define KTILE(TT, BUF)                                                                  \
    {                                                                                   \
        const int kt2 = ((TT)+2 < nt ? (TT)+2 : nt-1) * 64;                             \
        const int aB  = ((BUF)*2 + wm) * 8192;                                          \
        const int bB  = 32768 + ((BUF)*2 + (wn >> 1)) * 8192;                           \
        const int aBo = (((BUF)^1)*2 + wm) * 8192;                                      \
        const int bBo = 32768 + (((BUF)^1)*2 + (wn >> 1)) * 8192;                       \
        /* s0: (0,0,k0) */                                                              \
        RD_A(a1, aB, 0, 1) RD_B(b11, bB, 1, 1)                                          \
        SEG_MID(6)  MFMA8(a0, b00, 0, 0)  SEG_CUT                                       \
        /* s1: (0,0,k1) */                                                              \
        SEG_MID(0)  MFMA8(a1, b01, 0, 0)  SEG_CUT                                       \
        /* s2: (0,1,k0) */                                                              \
        SEG_MID(6)  MFMA8(a0, b10, 0, 2)  SEG_CUT                                       \
        /* s3: (0,1,k1) + stage B0(t+2) [bB reads drained at s1 lgkm(0)] */             \
        RD_A(a0, aB, 1, 0)                                                              \
        stage_half(Wptr, n0,       kt2, K, lds + (32768 + ((BUF)*2)*8192), tid);        \
        SEG_MID(4)  MFMA8(a1, b11, 0, 2)  SEG_CUT                                       \
        /* s4: (1,0,k0) + stage B1(t+2) + vmcnt gate pre-barrier */                     \
        RD_A(a1, aB, 1, 1)                                                              \
        stage_half(Wptr, n0 + 128, kt2, K, lds + (32768 + ((BUF)*2+1)*8192), tid);      \
        asm volatile("s_waitcnt vmcnt(4)" ::: "memory");                                \
        SEG_MID(4)  MFMA8(a0, b00, 4, 0)  SEG_CUT                                       \
        /* s5: (1,0,k1) */                                                              \
        RD_B(b00, bBo, 0, 0)                                                            \
        SEG_MID(2)  MFMA8(a1, b01, 4, 0)  SEG_CUT                                       \
        /* s6: (1,1,k0) */                                                              \
        RD_B(b01, bBo, 0, 1)                                                            \
        SEG_MID(4)  MFMA8(a0, b10, 4, 2)  SEG_CUT                                       \
        /* s7: (1,1,k1) + stage A(t+2) [aB reads drained at s5 lgkm(2)] */              \
        RD_B(b10, bBo, 1, 0) RD_A(a0, aBo, 0, 0)                                        \
        stage_half(Aptr, m0,       kt2, K, lds + (((BUF)*2)*8192), tid);                \
        stage_half(Aptr, m0 + 128, kt2, K, lds + (((BUF)*2+1)*8192), tid);              \
        SEG_MID(6)  MFMA8(a1, b11, 4, 2)  SEG_CUT                                       \
    }

__global__ __launch_bounds__(512) void gemm_8ph(const u16* __restrict__ Xraw,
                                                const u16* __restrict__ Xconv,
                                                const u16* __restrict__ Wmat,
                                                const void* __restrict__ bias,
                                                void* __restrict__ out,
                                                const int* __restrict__ flags,
                                                int M, int N, int K) {
    __shared__ __align__(16) u16 lds[65536];   // 128 KiB

    const int mode = flags[0];
    const u16* Aptr = (mode == 1) ? Xraw : Xconv;
    const u16* Wptr = Wmat;

    const int tid  = threadIdx.x;
    const int lane = tid & 63;
    const int wid  = tid >> 6;
    const int wm   = wid >> 2;        // 0..1 (M)
    const int wn   = wid & 3;         // 0..3 (N)
    const int lm   = lane & 15;
    const int kg   = lane >> 4;
    const int bh   = (wn & 1) * 64;
    const int swzu = (lm & 7) * 8;                 // 8*(row&7)
    const int cc0  = (kg * 8) ^ swzu;
    const int cc1  = (32 + kg * 8) ^ swzu;

    const int gn = N / 256;
    const int b  = blockIdx.x;
    const int per = gridDim.x >> 3;
    const int sw = ((per << 3) == (int)gridDim.x) ? ((b & 7) * per + (b >> 3)) : b;
    const int m0 = (sw / gn) * 256;
    const int n0 = (sw % gn) * 256;

    const int nt = K >> 6;

    bf16x8 a0[4], a1[4];
    bf16x8 b00[2], b01[2], b10[2], b11[2];
    f32x4 acc[8][4] = {};

    // prologue: stage tiles 0 and 1 fully (16 gloads), retire tile0's, pre-read s0 operands
    stage_half(Aptr, m0,       0,  K, lds + 0,                tid);
    stage_half(Aptr, m0 + 128, 0,  K, lds + 8192,             tid);
    stage_half(Wptr, n0,       0,  K, lds + 32768,            tid);
    stage_half(Wptr, n0 + 128, 0,  K, lds + 32768 + 8192,     tid);
    stage_half(Aptr, m0,       64, K, lds + 2 * 8192,         tid);
    stage_half(Aptr, m0 + 128, 64, K, lds + 3 * 8192,         tid);
    stage_half(Wptr, n0,       64, K, lds + 32768 + 2 * 8192, tid);
    stage_half(Wptr, n0 + 128, 64, K, lds + 32768 + 3 * 8192, tid);
    asm volatile("s_waitcnt vmcnt(8)" ::: "memory");
    __builtin_amdgcn_s_barrier();
    __builtin_amdgcn_sched_barrier(0);
    // pre-reads for tile0 s0: b00,b01,b10,a0 from buf0 (drained by s0's lgkm(6))
    {
        const int aB = wm * 8192;
        const int bB = 32768 + (wn >> 1) * 8192;
        RD_B(b00, bB, 0, 0)
        RD_B(b01, bB, 0, 1)
        RD_B(b10, bB, 1, 0)
        RD_A(a0,  aB, 0, 0)
    }
    __builtin_amdgcn_sched_barrier(0);

    for (int t = 0; t < nt; t += 2) {
        KTILE(t, 0)
        KTILE(t + 1, 1)
    }

    // ---- coalesced epilogue: per-wave LDS transpose, compiler-scheduled ----
    asm volatile("s_waitcnt vmcnt(0)" ::: "memory");   // stale clamped prefetches drained
    __syncthreads();                                   // all waves' K-loop LDS reads done
    float* fl = (float*)lds;
    const int wb   = wid * 1056;                 // 16 rows x 66 floats per wave (conflict-free)
    const int rr4  = (lane >> 4) * 4;
    const int ocol = n0 + wn * 64 + lane;
    const float bvf = load_bias(bias, ocol, mode);
    #pragma unroll
    for (int i = 0; i < 8; ++i) {
        #pragma unroll
        for (int j = 0; j < 4; ++j)
            #pragma unroll
            for (int r = 0; r < 4; ++r)
                fl[wb + (rr4 + r) * 66 + j * 16 + lm] = acc[i][j][r];
        float vals[16];
        #pragma unroll
        for (int rr = 0; rr < 16; ++rr)
            vals[rr] = fl[wb + rr * 66 + lane];
        #pragma unroll
        for (int rr = 0; rr < 16; ++rr) {
            const int row = m0 + wm * 128 + i * 16 + rr;
            store_out(out, (size_t)row * N + ocol, vals[rr] + bvf, mode);
        }
    }
}

// ---------------- fallback (tiny ws): fused 128-tile ----------------
__global__ __launch_bounds__(256) void gemm_fallback(const void* __restrict__ x,
                                                     const uint8_t* __restrict__ qraw,
                                                     const void* __restrict__ bias,
                                                     void* __restrict__ out,
                                                     const int* __restrict__ flags,
                                                     int M, int N, int K, int has_flags) {
    __shared__ __align__(16) u16 lA[128 * 64];
    __shared__ __align__(16) u16 lB[128 * 64];

    const int mode = has_flags ? flags[0] : 0;
    const int qm   = has_flags ? flags[1] : 0;

    const int tid  = threadIdx.x;
    const int lane = tid & 63;
    const int wid  = tid >> 6;
    const int gn   = N / 128;

    const int b   = blockIdx.x;
    const int per = gridDim.x >> 3;
    const int sw  = ((per << 3) == (int)gridDim.x) ? ((b & 7) * per + (b >> 3)) : b;
    const int m0  = (sw / gn) * 128;
    const int n0  = (sw % gn) * 128;

    const int wm = wid >> 1, wn = wid & 1;
    const int lm = lane & 15;
    const int kg = lane >> 4;
    const int rowQ = tid >> 1, halfQ = tid & 1;

    f32x4 acc[4][4] = {};

    for (int k0 = 0; k0 < K; k0 += 64) {
        #pragma unroll
        for (int rep = 0; rep < 4; ++rep) {
            const int c = rep * 256 + tid;
            const int row = c >> 3, col = (c & 7) * 8;
            union { u16 h[8]; uint4 v; } o;
            if (mode == 0) {
                const float4* xf = (const float4*)x + ((size_t)(m0 + row) * K + k0 + col) / 4;
                float4 a = xf[0], b2 = xf[1];
                o.h[0] = f2bf(a.x);  o.h[1] = f2bf(a.y);  o.h[2] = f2bf(a.z);  o.h[3] = f2bf(a.w);
                o.h[4] = f2bf(b2.x); o.h[5] = f2bf(b2.y); o.h[6] = f2bf(b2.z); o.h[7] = f2bf(b2.w);
            } else {
                uint4 v = *(const uint4*)((const u16*)x + (size_t)(m0 + row) * K + k0 + col);
                if (mode == 1) o.v = v;
                else {
                    const u16* hh = (const u16*)&v;
                    #pragma unroll
                    for (int i = 0; i < 8; ++i) o.h[i] = f2bf(h2f(hh[i]));
                }
            }
            *(uint4*)&lA[row * 64 + col] = o.v;
        }
        {
            const size_t blk = (size_t)(n0 + rowQ) * (K >> 5) + (k0 >> 5) + halfQ;
            uint32_t bb[18];
            if (qm == 0) {
                const uint8_t* p = qraw + blk * 18;
                #pragma unroll
                for (int i = 0; i < 18; ++i) bb[i] = p[i];
            } else {
                const int* p = (const int*)qraw + blk * 18;
                #pragma unroll
                for (int i = 0; i < 18; ++i) bb[i] = ((uint32_t)p[i]) & 0xFFu;
            }
            const float d = h2f((u16)(bb[0] | (bb[1] << 8)));
            union { u16 h[32]; uint4 v[4]; } o;
            #pragma unroll
            for (int i = 0; i < 16; ++i) {
                o.h[i]      = f2bf(d * (float)((int)(bb[2 + i] & 15u) - 8));
                o.h[16 + i] = f2bf(d * (float)((int)(bb[2 + i] >> 4) - 8));
            }
            uint4* dst = (uint4*)&lB[rowQ * 64 + halfQ * 32];
            dst[0] = o.v[0]; dst[1] = o.v[1]; dst[2] = o.v[2]; dst[3] = o.v[3];
        }
        __syncthreads();

        #pragma unroll
        for (int kk = 0; kk < 2; ++kk) {
            bf16x8 av[4], bv[4];
            #pragma unroll
            for (int i = 0; i < 4; ++i) {
                av[i] = *(const bf16x8*)&lA[(wm * 64 + i * 16 + lm) * 64 + kk * 32 + kg * 8];
                bv[i] = *(const bf16x8*)&lB[(wn * 64 + i * 16 + lm) * 64 + kk * 32 + kg * 8];
            }
            #pragma unroll
            for (int i = 0; i < 4; ++i)
                #pragma unroll
                for (int j = 0; j < 4; ++j)
                    acc[i][j] = __builtin_amdgcn_mfma_f32_16x16x32_bf16(av[i], bv[j], acc[i][j], 0, 0, 0);
        }
        __syncthreads();
    }

    const int rg = (lane >> 4) * 4;
    #pragma unroll
    for (int j = 0; j < 4; ++j) {
        const int col = n0 + wn * 64 + j * 16 + lm;
        const float bvf = load_bias(bias, col, mode);
        #pragma unroll
        for (int i = 0; i < 4; ++i) {
            const int row = m0 + wm * 64 + i * 16 + rg;
            #pragma unroll
            for (int r = 0; r < 4; ++r)
                store_out(out, (size_t)(row + r) * N + col, acc[i][j][r] + bvf, mode);
        }
    }
}

extern "C" void kernel_launch(void* const* d_in, const int* in_sizes, int n_in,
                              void* d_out, int out_size, void* d_ws, size_t ws_size,
                              hipStream_t stream) {
    const void*    x    = d_in[0];
    const uint8_t* qw   = (const uint8_t*)d_in[1];
    const void*    bias = d_in[2];

    const int N = in_sizes[2];
    const int row_elems = in_sizes[1] / N;
    const int K = (row_elems / 18) * 32;
    const int M = in_sizes[0] / K;

    const size_t offW = 256;
    const size_t offX = offW + (size_t)N * K * 2;
    const size_t need = offX + (size_t)M * K * 2;

    const int nt = K >> 6;
    const bool big_ok = (M % 256 == 0) && (N % 256 == 0) && (nt >= 4) && ((nt & 1) == 0);

    if (ws_size >= need && big_ok) {
        int* flags = (int*)d_ws;
        u16* W = (u16*)((char*)d_ws + offW);
        u16* X = (u16*)((char*)d_ws + offX);
        detect_kernel<<<1, 64, 0, stream>>>((const uint32_t*)x, (const uint32_t*)qw, flags);
        const int nblocks = N * (K >> 5);
        const int nblk_dq = (nblocks + 255) / 256;
        const size_t n8 = (size_t)M * K / 8;
        const int nblk_cv = (int)((n8 + 255) / 256);
        prepass_kernel<<<nblk_dq + nblk_cv, 256, 0, stream>>>(qw, x, W, X, nblocks, n8,
                                                              nblk_dq, flags);
        gemm_8ph<<<(M / 256) * (N / 256), 512, 0, stream>>>((const u16*)x, X, W, bias,
                                                            d_out, flags, M, N, K);
    } else if (ws_size >= 16) {
        int* flags = (int*)d_ws;
        detect_kernel<<<1, 64, 0, stream>>>((const uint32_t*)x, (const uint32_t*)qw, flags);
        gemm_fallback<<<(M / 128) * (N / 128), 256, 0, stream>>>(x, qw, bias, d_out, flags, M, N, K, 1);
    } else {
        gemm_fallback<<<(M / 128) * (N / 128), 256, 0, stream>>>(x, qw, bias, d_out, nullptr, M, N, K, 0);
    }
}

// Round 12
// 278.135 us; speedup vs baseline: 1.2042x; 1.0021x over previous
//
#include <hip/hip_runtime.h>
#include <stdint.h>

typedef unsigned short u16;
typedef __attribute__((ext_vector_type(8))) __bf16 bf16x8;
typedef __attribute__((ext_vector_type(4))) float f32x4;

// ---------------- scalar helpers ----------------
__device__ __forceinline__ u16 f2bf(float f) {
    uint32_t u = __float_as_uint(f);
    u += 0x7FFF + ((u >> 16) & 1);   // RNE
    return (u16)(u >> 16);
}
__device__ __forceinline__ float bf2f(u16 b) {
    return __uint_as_float(((uint32_t)b) << 16);
}
__device__ __forceinline__ float h2f(u16 h) {
    float r; uint32_t x = h;
    asm volatile("v_cvt_f32_f16_e32 %0, %1" : "=v"(r) : "v"(x));
    return r;
}
__device__ __forceinline__ u16 f2h(float f) {
    uint32_t r;
    asm volatile("v_cvt_f16_f32_e32 %0, %1" : "=v"(r) : "v"(f));
    return (u16)r;
}

// ---------------- dtype detection ----------------
// flags[0]: x/bias/out mode: 0=float32, 1=bf16(u16), 2=fp16(u16)
// flags[1]: qweight mode:    0=packed bytes, 1=one byte per int32
__global__ void detect_kernel(const uint32_t* __restrict__ xw,
                              const uint32_t* __restrict__ qw,
                              int* __restrict__ flags) {
    if (blockIdx.x | threadIdx.x) return;
    bool allz = true;
    for (int i = 0; i < 64; ++i) allz = allz && ((xw[i] & 0x1FFFu) == 0u);
    int mode;
    if (allz) mode = 0;
    else {
        const u16* xh = (const u16*)xw;
        int tiny = 0;
        for (int i = 0; i < 256; ++i) {
            u16 mag = xh[i] & 0x7FFF;
            if (mag != 0 && (mag >> 7) < 118) ++tiny;
        }
        mode = (tiny >= 16) ? 2 : 1;
    }
    bool bytes = false;
    for (int i = 0; i < 64; ++i) bytes = bytes || (qw[i] > 255u);
    flags[0] = mode;
    flags[1] = bytes ? 0 : 1;
}

// ---------------- fused prepass: dequant (role A) + x->bf16 convert (role B) ----------------
__global__ __launch_bounds__(256) void prepass_kernel(const uint8_t* __restrict__ qraw,
                                                      const void* __restrict__ x,
                                                      u16* __restrict__ W,
                                                      u16* __restrict__ X,
                                                      int nblocks, size_t n8, int nblk_dq,
                                                      const int* __restrict__ flags) {
    if ((int)blockIdx.x < nblk_dq) {
        // ---- dequant role (vectorized fetch) ----
        const int qm = flags[1];
        const int t = blockIdx.x * 256 + threadIdx.x;
        if (t >= nblocks) return;
        float d;
        uint32_t qsw[4];
        if (qm == 0) {
            const uint8_t* p = qraw + (size_t)t * 18;
            if (t & 1) {                         // byte offset ≡ 2 (mod 4)
                d = h2f(*(const u16*)p);
                const uint4 q = *(const uint4*)(p + 2);   // 4-aligned
                qsw[0] = q.x; qsw[1] = q.y; qsw[2] = q.z; qsw[3] = q.w;
            } else {                             // 4-aligned block start
                const uint32_t* pw = (const uint32_t*)p;
                const uint32_t d0 = pw[0], d1 = pw[1], d2 = pw[2], d3 = pw[3];
                const uint32_t d4 = (t + 1 < nblocks) ? pw[4]
                                                      : (uint32_t)*(const u16*)(p + 16);
                d = h2f((u16)(d0 & 0xFFFF));
                qsw[0] = (d0 >> 16) | (d1 << 16);
                qsw[1] = (d1 >> 16) | (d2 << 16);
                qsw[2] = (d2 >> 16) | (d3 << 16);
                qsw[3] = (d3 >> 16) | (d4 << 16);
            }
        } else {                                 // one byte per int32
            const int* p = (const int*)qraw + (size_t)t * 18;
            uint32_t b[18];
            #pragma unroll
            for (int i = 0; i < 18; ++i) b[i] = ((uint32_t)p[i]) & 0xFFu;
            d = h2f((u16)(b[0] | (b[1] << 8)));
            #pragma unroll
            for (int k = 0; k < 4; ++k)
                qsw[k] = b[2 + 4 * k] | (b[3 + 4 * k] << 8) | (b[4 + 4 * k] << 16) | (b[5 + 4 * k] << 24);
        }
        union { u16 h[32]; uint4 v[4]; } o;
        #pragma unroll
        for (int i = 0; i < 16; ++i) {
            const uint32_t byte = (qsw[i >> 2] >> ((i & 3) * 8)) & 0xFFu;
            o.h[i]      = f2bf(d * (float)((int)(byte & 15u) - 8));
            o.h[16 + i] = f2bf(d * (float)((int)(byte >> 4) - 8));
        }
        uint4* dst = (uint4*)(W + (size_t)t * 32);
        dst[0] = o.v[0]; dst[1] = o.v[1]; dst[2] = o.v[2]; dst[3] = o.v[3];
    } else {
        // ---- convert role ----
        const int mode = flags[0];
        if (mode == 1) return;                   // already bf16, GEMM reads d_in[0] directly
        const size_t t = (size_t)(blockIdx.x - nblk_dq) * 256 + threadIdx.x;
        if (t >= n8) return;
        union { u16 h[8]; uint4 v; } o;
        if (mode == 0) {
            const float4* xf = (const float4*)x;
            float4 a = xf[2 * t], b = xf[2 * t + 1];
            o.h[0] = f2bf(a.x); o.h[1] = f2bf(a.y); o.h[2] = f2bf(a.z); o.h[3] = f2bf(a.w);
            o.h[4] = f2bf(b.x); o.h[5] = f2bf(b.y); o.h[6] = f2bf(b.z); o.h[7] = f2bf(b.w);
        } else {
            uint4 v = ((const uint4*)x)[t];
            const u16* hh = (const u16*)&v;
            #pragma unroll
            for (int i = 0; i < 8; ++i) o.h[i] = f2bf(h2f(hh[i]));
        }
        ((uint4*)X)[t] = o.v;
    }
}

// ---------------- epilogue helpers ----------------
__device__ __forceinline__ float load_bias(const void* bias, int col, int mode) {
    if (mode == 0) return ((const float*)bias)[col];
    u16 b = ((const u16*)bias)[col];
    return (mode == 1) ? bf2f(b) : h2f(b);
}
__device__ __forceinline__ void store_out(void* out, size_t idx, float v, int mode) {
    if (mode == 0)      ((float*)out)[idx] = v;
    else if (mode == 1) ((u16*)out)[idx] = f2bf(v);
    else                ((u16*)out)[idx] = f2h(v);
}

// ---------------- 256x256 8-subphase pipelined GEMM (r11 skeleton, rebalanced lgkm) ----------------
// LDS (u16): A(buf,half) at (buf*2+half)*8192 ; B at 32768 + (buf*2+half)*8192.
// Swizzle: LDS[row][col ^ 8*(row&7)], both staged (global src pre-swizzled) and read.
// Read placement (per K-tile): s0: a1(4) | s1: b11(2) | s3: a0(4) | s4: a1(4)
//   | s5: b00'(2) | s6: b01'(2) | s7: b10'(2)+a0'(4).  24 b128/wave.
// lgkm ledger (FIFO, steady state; entering s0 = 10 outstanding):
//   s0: +4 -> 14, need a0,b00 -> lgkm(4) | s1: +2 -> 6, need a1 -> lgkm(2)
//   s2: 2 -> lgkm(0) [drains b11: required by B1-stage chain s4-pre=>s3-bar=>s2-wait]
//   s3: +4 -> lgkm(4) free | s4: +4 -> 8, need a0 -> lgkm(4) | s5: +2 -> 6, need a1 -> lgkm(2)
//   s6: +2 -> 4 free lgkm(4) | s7: +6 -> 10 free lgkm(10)
// Stage safety: B0@s3-pre (b00,b01 drained s0-wait, chain via s2-bar);
//   B1@s4-pre (b10 s0-wait, b11 s2-wait, chain via s3-bar);
//   A@s7-pre (a0-refill s4-wait, a1-refill s5-wait, chain via s6-bar).
// vmcnt(4) pre-mid at s4: drains B0B1(t+1)+A(t+1) -> buf^1 ready for s5+ reads.
__device__ __forceinline__ void stage_half(const u16* __restrict__ G, int row0, int k0,
                                           int kstride, u16* dstreg, int tid) {
    const int l = tid & 63, w = tid >> 6;
    const int r = w * 8 + (l >> 3);
    const int c = ((l & 7) * 8) ^ (((l >> 3) & 7) * 8);   // col ^ 8*(row&7)
    #pragma unroll
    for (int ch = 0; ch < 2; ++ch) {
        const u16* src = G + (size_t)(row0 + ch * 64 + r) * kstride + (k0 + c);
        u16* dst = dstreg + ch * 4096 + w * 512;     // wave-uniform; HW adds lane*16B
        __builtin_amdgcn_global_load_lds(
            (const __attribute__((address_space(1))) uint32_t*)src,
            (__attribute__((address_space(3))) uint32_t*)dst, 16, 0, 0);
    }
}

#define SEG_MID(N)  __builtin_amdgcn_s_barrier();                      \
                    asm volatile("s_waitcnt lgkmcnt(" #N ")");         \
                    __builtin_amdgcn_sched_barrier(0);                 \
                    __builtin_amdgcn_s_setprio(1);

#define SEG_CUT     __builtin_amdgcn_s_setprio(0);                     \
                    __builtin_amdgcn_sched_barrier(0);

#define RD_A(DST, BASE, HM, KK)                                                         \
    _Pragma("unroll")                                                                   \
    for (int i = 0; i < 4; ++i)                                                         \
        DST[i] = *(const bf16x8*)&lds[(BASE) + ((HM)*64 + i*16 + lm)*64 + ((KK) ? cc1 : cc0)];

#define RD_B(DST, BASE, HN, KK)                                                         \
    _Pragma("unroll")                                                                   \
    for (int j = 0; j < 2; ++j)                                                         \
        DST[j] = *(const bf16x8*)&lds[(BASE) + (bh + (HN)*32 + j*16 + lm)*64 + ((KK) ? cc1 : cc0)];

#define MFMA8(ASET, BSET, R, C)                                                         \
    _Pragma("unroll")                                                                   \
    for (int i = 0; i < 4; ++i)                                                         \
        _Pragma("unroll")                                                               \
        for (int j = 0; j < 2; ++j)                                                     \
            acc[(R)+i][(C)+j] = __builtin_amdgcn_mfma_f32_16x16x32_bf16(                \
                ASET[i], BSET[j], acc[(R)+i][(C)+j], 0, 0, 0);

#define KTILE(TT, BUF)                                                                  \
    {                                                                                   \
        const int kt2 = ((TT)+2 < nt ? (TT)+2 : nt-1) * 64;                             \
        const int aB  = ((BUF)*2 + wm) * 8192;                                          \
        const int bB  = 32768 + ((BUF)*2 + (wn >> 1)) * 8192;                           \
        const int aBo = (((BUF)^1)*2 + wm) * 8192;                                      \
        const int bBo = 32768 + (((BUF)^1)*2 + (wn >> 1)) * 8192;                       \
        /* s0: (0,0,k0) */                                                              \
        RD_A(a1, aB, 0, 1)                                                              \
        SEG_MID(4)  MFMA8(a0, b00, 0, 0)  SEG_CUT                                       \
        /* s1: (0,0,k1) */                                                              \
        RD_B(b11, bB, 1, 1)                                                             \
        SEG_MID(2)  MFMA8(a1, b01, 0, 0)  SEG_CUT                                       \
        /* s2: (0,1,k0) [lgkm(0) drains b11 for B1-stage chain] */                      \
        SEG_MID(0)  MFMA8(a0, b10, 0, 2)  SEG_CUT                                       \
        /* s3: (0,1,k1) + stage B0(t+2) [b00,b01 drained s0-wait] */                    \
        RD_A(a0, aB, 1, 0)                                                              \
        stage_half(Wptr, n0,       kt2, K, lds + (32768 + ((BUF)*2)*8192), tid);        \
        SEG_MID(4)  MFMA8(a1, b11, 0, 2)  SEG_CUT                                       \
        /* s4: (1,0,k0) + stage B1(t+2) + vmcnt gate pre-barrier */                     \
        RD_A(a1, aB, 1, 1)                                                              \
        stage_half(Wptr, n0 + 128, kt2, K, lds + (32768 + ((BUF)*2+1)*8192), tid);      \
        asm volatile("s_waitcnt vmcnt(4)" ::: "memory");                                \
        SEG_MID(4)  MFMA8(a0, b00, 4, 0)  SEG_CUT                                       \
        /* s5: (1,0,k1) */                                                              \
        RD_B(b00, bBo, 0, 0)                                                            \
        SEG_MID(2)  MFMA8(a1, b01, 4, 0)  SEG_CUT                                       \
        /* s6: (1,1,k0) */                                                              \
        RD_B(b01, bBo, 0, 1)                                                            \
        SEG_MID(4)  MFMA8(a0, b10, 4, 2)  SEG_CUT                                       \
        /* s7: (1,1,k1) + stage A(t+2) [a0/a1 refills drained s4/s5 waits] */           \
        RD_B(b10, bBo, 1, 0) RD_A(a0, aBo, 0, 0)                                        \
        stage_half(Aptr, m0,       kt2, K, lds + (((BUF)*2)*8192), tid);                \
        stage_half(Aptr, m0 + 128, kt2, K, lds + (((BUF)*2+1)*8192), tid);              \
        SEG_MID(10)  MFMA8(a1, b11, 4, 2)  SEG_CUT                                      \
    }

__global__ __launch_bounds__(512) void gemm_8ph(const u16* __restrict__ Xraw,
                                                const u16* __restrict__ Xconv,
                                                const u16* __restrict__ Wmat,
                                                const void* __restrict__ bias,
                                                void* __restrict__ out,
                                                const int* __restrict__ flags,
                                                int M, int N, int K) {
    __shared__ __align__(16) u16 lds[65536];   // 128 KiB

    const int mode = flags[0];
    const u16* Aptr = (mode == 1) ? Xraw : Xconv;
    const u16* Wptr = Wmat;

    const int tid  = threadIdx.x;
    const int lane = tid & 63;
    const int wid  = tid >> 6;
    const int wm   = wid >> 2;        // 0..1 (M)
    const int wn   = wid & 3;         // 0..3 (N)
    const int lm   = lane & 15;
    const int kg   = lane >> 4;
    const int bh   = (wn & 1) * 64;
    const int swzu = (lm & 7) * 8;                 // 8*(row&7)
    const int cc0  = (kg * 8) ^ swzu;
    const int cc1  = (32 + kg * 8) ^ swzu;

    const int gn = N / 256;
    const int b  = blockIdx.x;
    const int per = gridDim.x >> 3;
    const int sw = ((per << 3) == (int)gridDim.x) ? ((b & 7) * per + (b >> 3)) : b;
    const int m0 = (sw / gn) * 256;
    const int n0 = (sw % gn) * 256;

    const int nt = K >> 6;

    bf16x8 a0[4], a1[4];
    bf16x8 b00[2], b01[2], b10[2], b11[2];
    f32x4 acc[8][4] = {};

    // prologue: stage tiles 0 and 1 fully (16 gloads), retire tile0's, pre-read s0 operands
    stage_half(Aptr, m0,       0,  K, lds + 0,                tid);
    stage_half(Aptr, m0 + 128, 0,  K, lds + 8192,             tid);
    stage_half(Wptr, n0,       0,  K, lds + 32768,            tid);
    stage_half(Wptr, n0 + 128, 0,  K, lds + 32768 + 8192,     tid);
    stage_half(Aptr, m0,       64, K, lds + 2 * 8192,         tid);
    stage_half(Aptr, m0 + 128, 64, K, lds + 3 * 8192,         tid);
    stage_half(Wptr, n0,       64, K, lds + 32768 + 2 * 8192, tid);
    stage_half(Wptr, n0 + 128, 64, K, lds + 32768 + 3 * 8192, tid);
    asm volatile("s_waitcnt vmcnt(8)" ::: "memory");
    __builtin_amdgcn_s_barrier();
    __builtin_amdgcn_sched_barrier(0);
    // pre-reads for tile0 s0: b00,b01,b10,a0 from buf0 (10 reads = steady-state entry)
    {
        const int aB = wm * 8192;
        const int bB = 32768 + (wn >> 1) * 8192;
        RD_B(b00, bB, 0, 0)
        RD_B(b01, bB, 0, 1)
        RD_B(b10, bB, 1, 0)
        RD_A(a0,  aB, 0, 0)
    }
    __builtin_amdgcn_sched_barrier(0);

    for (int t = 0; t < nt; t += 2) {
        KTILE(t, 0)
        KTILE(t + 1, 1)
    }

    // ---- coalesced epilogue: per-wave LDS transpose, compiler-scheduled ----
    asm volatile("s_waitcnt vmcnt(0)" ::: "memory");   // stale clamped prefetches drained
    __syncthreads();                                   // all waves' K-loop LDS reads done
    float* fl = (float*)lds;
    const int wb   = wid * 1056;                 // 16 rows x 66 floats per wave (conflict-free)
    const int rr4  = (lane >> 4) * 4;
    const int ocol = n0 + wn * 64 + lane;
    const float bvf = load_bias(bias, ocol, mode);
    #pragma unroll
    for (int i = 0; i < 8; ++i) {
        #pragma unroll
        for (int j = 0; j < 4; ++j)
            #pragma unroll
            for (int r = 0; r < 4; ++r)
                fl[wb + (rr4 + r) * 66 + j * 16 + lm] = acc[i][j][r];
        float vals[16];
        #pragma unroll
        for (int rr = 0; rr < 16; ++rr)
            vals[rr] = fl[wb + rr * 66 + lane];
        #pragma unroll
        for (int rr = 0; rr < 16; ++rr) {
            const int row = m0 + wm * 128 + i * 16 + rr;
            store_out(out, (size_t)row * N + ocol, vals[rr] + bvf, mode);
        }
    }
}

// ---------------- fallback (tiny ws): fused 128-tile ----------------
__global__ __launch_bounds__(256) void gemm_fallback(const void* __restrict__ x,
                                                     const uint8_t* __restrict__ qraw,
                                                     const void* __restrict__ bias,
                                                     void* __restrict__ out,
                                                     const int* __restrict__ flags,
                                                     int M, int N, int K, int has_flags) {
    __shared__ __align__(16) u16 lA[128 * 64];
    __shared__ __align__(16) u16 lB[128 * 64];

    const int mode = has_flags ? flags[0] : 0;
    const int qm   = has_flags ? flags[1] : 0;

    const int tid  = threadIdx.x;
    const int lane = tid & 63;
    const int wid  = tid >> 6;
    const int gn   = N / 128;

    const int b   = blockIdx.x;
    const int per = gridDim.x >> 3;
    const int sw  = ((per << 3) == (int)gridDim.x) ? ((b & 7) * per + (b >> 3)) : b;
    const int m0  = (sw / gn) * 128;
    const int n0  = (sw % gn) * 128;

    const int wm = wid >> 1, wn = wid & 1;
    const int lm = lane & 15;
    const int kg = lane >> 4;
    const int rowQ = tid >> 1, halfQ = tid & 1;

    f32x4 acc[4][4] = {};

    for (int k0 = 0; k0 < K; k0 += 64) {
        #pragma unroll
        for (int rep = 0; rep < 4; ++rep) {
            const int c = rep * 256 + tid;
            const int row = c >> 3, col = (c & 7) * 8;
            union { u16 h[8]; uint4 v; } o;
            if (mode == 0) {
                const float4* xf = (const float4*)x + ((size_t)(m0 + row) * K + k0 + col) / 4;
                float4 a = xf[0], b2 = xf[1];
                o.h[0] = f2bf(a.x);  o.h[1] = f2bf(a.y);  o.h[2] = f2bf(a.z);  o.h[3] = f2bf(a.w);
                o.h[4] = f2bf(b2.x); o.h[5] = f2bf(b2.y); o.h[6] = f2bf(b2.z); o.h[7] = f2bf(b2.w);
            } else {
                uint4 v = *(const uint4*)((const u16*)x + (size_t)(m0 + row) * K + k0 + col);
                if (mode == 1) o.v = v;
                else {
                    const u16* hh = (const u16*)&v;
                    #pragma unroll
                    for (int i = 0; i < 8; ++i) o.h[i] = f2bf(h2f(hh[i]));
                }
            }
            *(uint4*)&lA[row * 64 + col] = o.v;
        }
        {
            const size_t blk = (size_t)(n0 + rowQ) * (K >> 5) + (k0 >> 5) + halfQ;
            uint32_t bb[18];
            if (qm == 0) {
                const uint8_t* p = qraw + blk * 18;
                #pragma unroll
                for (int i = 0; i < 18; ++i) bb[i] = p[i];
            } else {
                const int* p = (const int*)qraw + blk * 18;
                #pragma unroll
                for (int i = 0; i < 18; ++i) bb[i] = ((uint32_t)p[i]) & 0xFFu;
            }
            const float d = h2f((u16)(bb[0] | (bb[1] << 8)));
            union { u16 h[32]; uint4 v[4]; } o;
            #pragma unroll
            for (int i = 0; i < 16; ++i) {
                o.h[i]      = f2bf(d * (float)((int)(bb[2 + i] & 15u) - 8));
                o.h[16 + i] = f2bf(d * (float)((int)(bb[2 + i] >> 4) - 8));
            }
            uint4* dst = (uint4*)&lB[rowQ * 64 + halfQ * 32];
            dst[0] = o.v[0]; dst[1] = o.v[1]; dst[2] = o.v[2]; dst[3] = o.v[3];
        }
        __syncthreads();

        #pragma unroll
        for (int kk = 0; kk < 2; ++kk) {
            bf16x8 av[4], bv[4];
            #pragma unroll
            for (int i = 0; i < 4; ++i) {
                av[i] = *(const bf16x8*)&lA[(wm * 64 + i * 16 + lm) * 64 + kk * 32 + kg * 8];
                bv[i] = *(const bf16x8*)&lB[(wn * 64 + i * 16 + lm) * 64 + kk * 32 + kg * 8];
            }
            #pragma unroll
            for (int i = 0; i < 4; ++i)
                #pragma unroll
                for (int j = 0; j < 4; ++j)
                    acc[i][j] = __builtin_amdgcn_mfma_f32_16x16x32_bf16(av[i], bv[j], acc[i][j], 0, 0, 0);
        }
        __syncthreads();
    }

    const int rg = (lane >> 4) * 4;
    #pragma unroll
    for (int j = 0; j < 4; ++j) {
        const int col = n0 + wn * 64 + j * 16 + lm;
        const float bvf = load_bias(bias, col, mode);
        #pragma unroll
        for (int i = 0; i < 4; ++i) {
            const int row = m0 + wm * 64 + i * 16 + rg;
            #pragma unroll
            for (int r = 0; r < 4; ++r)
                store_out(out, (size_t)(row + r) * N + col, acc[i][j][r] + bvf, mode);
        }
    }
}

extern "C" void kernel_launch(void* const* d_in, const int* in_sizes, int n_in,
                              void* d_out, int out_size, void* d_ws, size_t ws_size,
                              hipStream_t stream) {
    const void*    x    = d_in[0];
    const uint8_t* qw   = (const uint8_t*)d_in[1];
    const void*    bias = d_in[2];

    const int N = in_sizes[2];
    const int row_elems = in_sizes[1] / N;
    const int K = (row_elems / 18) * 32;
    const int M = in_sizes[0] / K;

    const size_t offW = 256;
    const size_t offX = offW + (size_t)N * K * 2;
    const size_t need = offX + (size_t)M * K * 2;

    const int nt = K >> 6;
    const bool big_ok = (M % 256 == 0) && (N % 256 == 0) && (nt >= 4) && ((nt & 1) == 0);

    if (ws_size >= need && big_ok) {
        int* flags = (int*)d_ws;
        u16* W = (u16*)((char*)d_ws + offW);
        u16* X = (u16*)((char*)d_ws + offX);
        detect_kernel<<<1, 64, 0, stream>>>((const uint32_t*)x, (const uint32_t*)qw, flags);
        const int nblocks = N * (K >> 5);
        const int nblk_dq = (nblocks + 255) / 256;
        const size_t n8 = (size_t)M * K / 8;
        const int nblk_cv = (int)((n8 + 255) / 256);
        prepass_kernel<<<nblk_dq + nblk_cv, 256, 0, stream>>>(qw, x, W, X, nblocks, n8,
                                                              nblk_dq, flags);
        gemm_8ph<<<(M / 256) * (N / 256), 512, 0, stream>>>((const u16*)x, X, W, bias,
                                                            d_out, flags, M, N, K);
    } else if (ws_size >= 16) {
        int* flags = (int*)d_ws;
        detect_kernel<<<1, 64, 0, stream>>>((const uint32_t*)x, (const uint32_t*)qw, flags);
        gemm_fallback<<<(M / 128) * (N / 128), 256, 0, stream>>>(x, qw, bias, d_out, flags, M, N, K, 1);
    } else {
        gemm_fallback<<<(M / 128) * (N / 128), 256, 0, stream>>>(x, qw, bias, d_out, nullptr, M, N, K, 0);
    }
}